// Round 11
// baseline (589.009 us; speedup 1.0000x reference)
//
#include <hip/hip_runtime.h>
#include <hip/hip_bf16.h>

#define HIDDEN 768
#define MLPH   3072
#define HEADS  12
#define HD     64
#define SEQ    1024
#define BATCH  16
#define MTOT   (BATCH*SEQ)   // 16384

typedef __attribute__((ext_vector_type(8))) short  short8;
typedef __attribute__((ext_vector_type(4))) short  short4x;
typedef __attribute__((ext_vector_type(8))) __bf16 bf16x8;
typedef __attribute__((ext_vector_type(4))) float  floatx4;

#define CL2 0.18033688011112042f   // 0.125 * log2(e): QK scale folded to exp2 domain

__device__ inline short f2bf(float f) {
  __hip_bfloat16 h = __float2bfloat16(f);
  return *reinterpret_cast<short*>(&h);
}

__device__ inline floatx4 mfma_bf16(short8 a, short8 b, floatx4 c) {
  return __builtin_amdgcn_mfma_f32_16x16x32_bf16(
      __builtin_bit_cast(bf16x8, a), __builtin_bit_cast(bf16x8, b), c, 0, 0, 0);
}

__device__ inline void gl_lds16(const short* g, short* l) {
  __builtin_amdgcn_global_load_lds(
      (const __attribute__((address_space(1))) unsigned int*)g,
      (__attribute__((address_space(3))) unsigned int*)l, 16, 0, 0);
}

// fast GELU: tanh form via v_exp_f32 + v_rcp_f32 (~10 VALU vs ~80 for erff).
// r7-validated: absmax unchanged (0.03125); MLP1 124 -> 99 us.
__device__ inline float gelu_f(float x) {
  float z = 0.7978845608028654f * (x + 0.044715f * x * x * x);
  float e = __builtin_amdgcn_exp2f(z * 2.8853900817779268f);  // exp(2z)
  float t = 1.0f - 2.0f * __builtin_amdgcn_rcpf(e + 1.0f);    // tanh(z)
  return 0.5f * x * (1.0f + t);
}

// ---------------- weight conversion (straight copies only) ----------------
__global__ __launch_bounds__(256) void conv_weights(
    const float* __restrict__ wq, const float* __restrict__ wk,
    const float* __restrict__ wv, const float* __restrict__ wo,
    short* __restrict__ wqkvb, short* __restrict__ wob)
{
  int i = blockIdx.x * 256 + threadIdx.x;
  const int HH = HIDDEN * HIDDEN;
  if (i < HH) {
    wqkvb[i]        = f2bf(wq[i]);
    wqkvb[HH + i]   = f2bf(wk[i]);
    wqkvb[2*HH + i] = f2bf(wv[i]);
    wob[i]          = f2bf(wo[i]);
  }
}

// ---------------- tiled f32->bf16 weight transpose: out[n][k] = in[k][n] ----
__global__ __launch_bounds__(256) void wtrans_kernel(
    const float* __restrict__ in, short* __restrict__ out, int RK, int CN)
{
  __shared__ float T[64][65];
  int n0 = blockIdx.x * 64, k0 = blockIdx.y * 64;
  int tx = threadIdx.x & 63, ty = threadIdx.x >> 6;   // 64 x 4
#pragma unroll
  for (int r = ty; r < 64; r += 4)
    T[r][tx] = in[(size_t)(k0 + r) * CN + n0 + tx];
  __syncthreads();
#pragma unroll
  for (int r = ty; r < 64; r += 4)
    out[(size_t)(n0 + r) * RK + k0 + tx] = f2bf(T[tx][r]);
}

// ---------------- layernorm (fp32 in, bf16 out) ----------------
__global__ __launch_bounds__(256) void ln_kernel(
    const float* __restrict__ x, const float* __restrict__ g,
    const float* __restrict__ b, short* __restrict__ out)
{
  int row = blockIdx.x;
  const float* xr = x + (size_t)row * HIDDEN;
  int t = threadIdx.x;
  float v0 = xr[t], v1 = xr[t + 256], v2 = xr[t + 512];
  float s  = v0 + v1 + v2;
  float s2 = v0*v0 + v1*v1 + v2*v2;
  for (int off = 32; off > 0; off >>= 1) {
    s  += __shfl_down(s, off);
    s2 += __shfl_down(s2, off);
  }
  __shared__ float red[8];
  __shared__ float stats[2];
  int wave = t >> 6;
  if ((t & 63) == 0) { red[wave] = s; red[4 + wave] = s2; }
  __syncthreads();
  if (t == 0) {
    float S  = red[0] + red[1] + red[2] + red[3];
    float S2 = red[4] + red[5] + red[6] + red[7];
    float mu  = S * (1.0f / HIDDEN);
    float var = S2 * (1.0f / HIDDEN) - mu * mu;
    stats[0] = mu;
    stats[1] = rsqrtf(var + 1e-5f);
  }
  __syncthreads();
  float mu = stats[0], rs = stats[1];
  short* orow = out + (size_t)row * HIDDEN;
  orow[t]       = f2bf((v0 - mu) * rs * g[t]       + b[t]);
  orow[t + 256] = f2bf((v1 - mu) * rs * g[t + 256] + b[t + 256]);
  orow[t + 512] = f2bf((v2 - mu) * rs * g[t + 512] + b[t + 512]);
}

// ---------------- BT-GEMM v4 (r7 champion — sync structure FROZEN) ---------
// C[M,N] = A[M,K] * B[N,K]^T. 2-slot LDS dbuf, 4 contiguous 256x32 regions
// per slot. 4 phases per 64-k step, 16 MFMA each; counted vmcnt (never 0
// mid-loop); per-phase lgkmcnt(0)+sched_barrier+setprio. All stages target
// the OTHER slot only (r9's current-slot staging raced). VSPLIT: QKV writes
// V-columns directly into the pre-swizzled vtg image.
template<int OUTMODE /*0=f32,1=bf16*/, bool BIAS, bool GELU_E, bool RES,
         bool SCALEQ = false, bool VSPLIT = false>
__global__ __launch_bounds__(512, 2) void gemm_bt2(
    const short* __restrict__ A, const short* __restrict__ B,
    const float* __restrict__ bias, const float* __restrict__ res,
    void* __restrict__ out, short* __restrict__ vout, int M, int N, int K)
{
  __shared__ alignas(16) short As[2][2][8192];   // [slot][ks][256x32] = 64 KiB
  __shared__ alignas(16) short Bs[2][2][8192];   // 64 KiB

  int tid = threadIdx.x;
  int lane = tid & 63, wave = tid >> 6;
  int wr = wave >> 2, wc = wave & 3;          // 2 x 4 wave grid -> 128x64/wave
  int quad = lane >> 4, lc = lane & 15;

  // ---- XCD-aware bijective block swizzle (T1) ----
  int nbx = gridDim.x;
  int nwg = nbx * gridDim.y;
  int orig = blockIdx.y * nbx + blockIdx.x;
  int q8 = nwg >> 3, r8 = nwg & 7;
  int xcd = orig & 7, sub = orig >> 3;
  int wg = (xcd < r8 ? xcd * (q8 + 1) : r8 * (q8 + 1) + (xcd - r8) * q8) + sub;
  int m0 = (wg / nbx) * 256;
  int n0 = (wg % nbx) * 256;

  int srow = tid >> 2;
  int skb  = (tid & 3) ^ ((srow >> 1) & 3);
  const short* ga = A + (size_t)(m0 + srow) * K + skb * 8;
  const short* gb = B + (size_t)(n0 + srow) * K + skb * 8;
  const size_t rowskip = (size_t)128 * K;
  int lb0 = wave * 512;   // wave-uniform LDS base (shorts); HW adds lane*16B

#define STAGE_R(MAT, gp, sl, ks, kt) {                         \
    const short* _g = (gp) + (size_t)(kt) * 64 + (ks) * 32;    \
    gl_lds16(_g,           &MAT[sl][ks][lb0]);                 \
    gl_lds16(_g + rowskip, &MAT[sl][ks][4096 + lb0]);          \
  }

  floatx4 acc[8][4];
#pragma unroll
  for (int i = 0; i < 8; ++i)
#pragma unroll
    for (int j = 0; j < 4; ++j) acc[i][j] = floatx4{0.f, 0.f, 0.f, 0.f};

  int apos = (quad ^ ((lc >> 1) & 3)) * 8;
#define RD(buf, r) (*(const short8*)&(buf)[(r) * 32 + apos])
#define MM4x4(IOFF)                                                     \
    _Pragma("unroll")                                                   \
    for (int i = 0; i < 4; ++i)                                         \
      _Pragma("unroll")                                                 \
      for (int j = 0; j < 4; ++j)                                       \
        acc[i + IOFF][j] = mfma_bf16(aF[i], bF[j], acc[i + IOFF][j]);

  int NK = K >> 6;   // 64-wide K-steps: K=768 -> 12, K=3072 -> 48

  STAGE_R(As, ga, 0, 0, 0); STAGE_R(Bs, gb, 0, 0, 0);
  STAGE_R(As, ga, 0, 1, 0); STAGE_R(Bs, gb, 0, 1, 0);

  for (int kt = 0; kt < NK; ++kt) {
    const int sl = kt & 1;
    const short (*as_)[8192] = As[sl];
    const short (*bs_)[8192] = Bs[sl];
    const int s2 = sl ^ 1;
    const bool st = (kt + 1 < NK);
    short8 aF[4], bF[4];

    // ===== ph0: ks0 x i0-3  (stage B-ks1(kt+1)) =====
    asm volatile("s_waitcnt vmcnt(2)" ::: "memory");
    __builtin_amdgcn_s_barrier();
    asm volatile("" ::: "memory");
#pragma unroll
    for (int i = 0; i < 4; ++i) aF[i] = RD(as_[0], wr * 128 + i * 16 + lc);
#pragma unroll
    for (int j = 0; j < 4; ++j) bF[j] = RD(bs_[0], wc * 64 + j * 16 + lc);
    if (st) STAGE_R(Bs, gb, s2, 1, kt + 1);
    asm volatile("s_waitcnt lgkmcnt(0)" ::: "memory");
    __builtin_amdgcn_sched_barrier(0);
    __builtin_amdgcn_s_setprio(1);
    MM4x4(0);
    __builtin_amdgcn_s_setprio(0);

    // ===== ph1: ks0 x i4-7  (stage B-ks0(kt+1)) =====
    __builtin_amdgcn_s_barrier();
    asm volatile("" ::: "memory");
#pragma unroll
    for (int i = 0; i < 4; ++i) aF[i] = RD(as_[0], wr * 128 + (i + 4) * 16 + lc);
    if (st) STAGE_R(Bs, gb, s2, 0, kt + 1);
    asm volatile("s_waitcnt lgkmcnt(0)" ::: "memory");
    __builtin_amdgcn_sched_barrier(0);
    __builtin_amdgcn_s_setprio(1);
    MM4x4(4);
    __builtin_amdgcn_s_setprio(0);

    // ===== ph2: ks1 x i0-3  (stage A-ks0(kt+1)) =====
    if (st) asm volatile("s_waitcnt vmcnt(4)" ::: "memory");
    else    asm volatile("s_waitcnt vmcnt(0)" ::: "memory");
    __builtin_amdgcn_s_barrier();
    asm volatile("" ::: "memory");
#pragma unroll
    for (int i = 0; i < 4; ++i) aF[i] = RD(as_[1], wr * 128 + i * 16 + lc);
#pragma unroll
    for (int j = 0; j < 4; ++j) bF[j] = RD(bs_[1], wc * 64 + j * 16 + lc);
    if (st) STAGE_R(As, ga, s2, 0, kt + 1);
    asm volatile("s_waitcnt lgkmcnt(0)" ::: "memory");
    __builtin_amdgcn_sched_barrier(0);
    __builtin_amdgcn_s_setprio(1);
    MM4x4(0);
    __builtin_amdgcn_s_setprio(0);

    // ===== ph3: ks1 x i4-7  (stage A-ks1(kt+1)) =====
    __builtin_amdgcn_s_barrier();
    asm volatile("" ::: "memory");
#pragma unroll
    for (int i = 0; i < 4; ++i) aF[i] = RD(as_[1], wr * 128 + (i + 4) * 16 + lc);
    if (st) STAGE_R(As, ga, s2, 1, kt + 1);
    asm volatile("s_waitcnt lgkmcnt(0)" ::: "memory");
    __builtin_amdgcn_sched_barrier(0);
    __builtin_amdgcn_s_setprio(1);
    MM4x4(4);
    __builtin_amdgcn_s_setprio(0);
  }
#undef STAGE_R
#undef RD
#undef MM4x4

  // epilogue: C row = quad*4+reg, col = lane&15 (m89-verified layout)
#pragma unroll
  for (int i = 0; i < 8; ++i)
#pragma unroll
    for (int j = 0; j < 4; ++j)
#pragma unroll
      for (int r = 0; r < 4; ++r) {
        int row = m0 + wr * 128 + i * 16 + quad * 4 + r;
        int col = n0 + wc * 64 + j * 16 + lc;
        float v = acc[i][j][r];
        if (BIAS)   v += bias[col];
        if (GELU_E) v = gelu_f(v);
        if (RES)    v += res[(size_t)row * N + col];
        if (SCALEQ && col < HIDDEN) v *= CL2;
        if (VSPLIT && col >= 2 * HIDDEN) {
          int b_ = row >> 10, rr = row & 1023, kt_ = rr >> 6, k_ = rr & 63;
          int ks_ = k_ >> 5, kk = k_ & 31;
          int hd = col - 2 * HIDDEN, h_ = hd >> 6, d_ = hd & 63;
          size_t idx = ((size_t)((b_ * HEADS + h_) * 16 + kt_)) * 4096
                     + ks_ * 2048 + d_ * 32
                     + (((kk >> 3) ^ ((d_ >> 1) & 3)) << 3) + (kk & 7);
          vout[idx] = f2bf(v);
        } else if (OUTMODE == 1) {
          ((short*)out)[(size_t)row * N + col] = f2bf(v);
        } else {
          ((float*)out)[(size_t)row * N + col] = v;
        }
      }
}

// ---------------- flash attention v5: K-dbuf, 1 barrier/kt, direct-V -------
// r10 post-mortem: attn had 2 full-drain __syncthreads per kt + V LDS
// roundtrip. Fixes (catalog #7 precedent: drop L2-fit V staging):
//  - V read DIRECT from global vtg: identity map Vs[idx]==vtg[kt*4096+idx],
//    wave read = contiguous 1KiB/instr, L2-hot (8 q-blocks share each tile).
//  - K double-buffered (Ks[2]); stage K(kt+1) into other slot AFTER the top
//    barrier (that slot's QK^T(kt-1) reads were lgkm-drained before every
//    wave reached this barrier). Own stage-writes vmcnt(0)-drained BEFORE
//    the next top barrier -> cross-wave publish correct. ONE barrier per kt.
__global__ __launch_bounds__(512) void attn_kernel(
    const short* __restrict__ qkv, const short* __restrict__ vtg,
    short* __restrict__ out)
{
  int qt = blockIdx.x;   // 0..7 (128 q rows each)
  int h  = blockIdx.y;   // 0..11
  int b  = blockIdx.z;   // batch within chunk
  int tid = threadIdx.x, lane = tid & 63, wave = tid >> 6;
  int quad = lane >> 4, lc = lane & 15;

  __shared__ alignas(16) short Qs[2 * 128 * 32];   // 16 KiB
  __shared__ alignas(16) short Ks[2][64 * 32];     // 16 KiB (K dbuf)
  __shared__ alignas(16) short Ps[8][16 * 72];     // 18 KiB, padded rows

  const int LDQ = 3 * HIDDEN;  // 2304
  const short* qb = qkv + (size_t)(b * SEQ) * LDQ + h * HD;
  const short* kb = qb + HIDDEN;
  const short* vt = vtg + (size_t)((b * HEADS + h) * 16) * 4096;

  // ---- stage Q (once) + K tile 0; prologue syncthreads drains both ----
  {
    int row = tid >> 2, blk = tid & 3;
    int kblk = blk ^ ((row >> 1) & 3);
#pragma unroll
    for (int t = 0; t < 2; ++t) {
      const short* g = qb + (size_t)(qt * 128 + row) * LDQ + t * 32 + kblk * 8;
      gl_lds16(g, &Qs[t * 4096 + wave * 512]);
    }
  }
  int srow = (tid >> 2) & 63;
  int sks  = tid >> 8;
  int skb  = (tid & 3) ^ ((srow >> 1) & 3);
  const short* kg0 = kb + (size_t)srow * LDQ + sks * 32 + skb * 8;
  gl_lds16(kg0, &Ks[0][wave * 512]);
  __syncthreads();   // Q + K0 resident (full drain)

  // hoisted Q fragments (B-operand: lane holds Q[q = wave*16+lc][d..])
  int pos = quad ^ ((lc >> 1) & 3);
  short8 aq[2];
#pragma unroll
  for (int ks = 0; ks < 2; ++ks)
    aq[ks] = *(const short8*)&Qs[ks * 4096 + (wave * 16 + lc) * 32 + pos * 8];

  floatx4 oacc[4];
#pragma unroll
  for (int n2 = 0; n2 < 4; ++n2) oacc[n2] = floatx4{0.f, 0.f, 0.f, 0.f};
  float lsum = 0.f;   // partial row-sum for q = wave*16+lc
  short* pw = &Ps[wave][0];

  for (int kt = 0; kt < 16; ++kt) {
    const int sl = kt & 1;
    // top: own K(kt) stage-writes (and stray bv loads) drained, then publish
    asm volatile("s_waitcnt vmcnt(0)" ::: "memory");
    __builtin_amdgcn_s_barrier();
    asm volatile("" ::: "memory");
    // stage K(kt+1) into the slot whose reads finished in iteration kt-1
    if (kt + 1 < 16)
      gl_lds16(kg0 + (size_t)((kt + 1) * 64) * LDQ, &Ks[sl ^ 1][wave * 512]);

    // ---- S^T = K Q^T : lane holds S^T[k = m2*16+quad*4+r][q = lc] ----
    floatx4 sacc[4];
#pragma unroll
    for (int m2 = 0; m2 < 4; ++m2) sacc[m2] = floatx4{0.f, 0.f, 0.f, 0.f};
#pragma unroll
    for (int ks = 0; ks < 2; ++ks) {
#pragma unroll
      for (int m2 = 0; m2 < 4; ++m2) {
        short8 ak = *(const short8*)&Ks[sl][ks * 2048 + (m2 * 16 + lc) * 32 + pos * 8];
        sacc[m2] = mfma_bf16(ak, aq[ks], sacc[m2]);
      }
    }

    // ---- exp2, accumulate l, pack 4 consecutive-k bf16 -> one b64 write ----
#pragma unroll
    for (int m2 = 0; m2 < 4; ++m2) {
      float p0 = exp2f(sacc[m2][0]);
      float p1 = exp2f(sacc[m2][1]);
      float p2 = exp2f(sacc[m2][2]);
      float p3 = exp2f(sacc[m2][3]);
      lsum += (p0 + p1) + (p2 + p3);
      short4x pk;
      pk[0] = f2bf(p0); pk[1] = f2bf(p1); pk[2] = f2bf(p2); pk[3] = f2bf(p3);
      *(short4x*)&pw[lc * 72 + m2 * 16 + quad * 4] = pk;
    }
    // wave-private LDS handoff: wait own ds ops, pin the schedule (rule 18)
    asm volatile("s_waitcnt lgkmcnt(0)" ::: "memory");
    __builtin_amdgcn_sched_barrier(0);

    // ---- O += P @ V  (A = P rows q=lc; B = V^T DIRECT from global) ----
    const short* vkt = vt + kt * 4096;
#pragma unroll
    for (int ks = 0; ks < 2; ++ks) {
      short8 ap = *(const short8*)&pw[lc * 72 + (ks * 4 + quad) * 8];
#pragma unroll
      for (int n2 = 0; n2 < 4; ++n2) {
        short8 bv = *(const short8*)&vkt[ks * 2048 + (n2 * 16 + lc) * 32 + pos * 8];
        oacc[n2] = mfma_bf16(ap, bv, oacc[n2]);
      }
    }
    // no trailing barrier: next iteration's top vmcnt(0)+barrier orders all
  }

  // ---- epilogue: reduce l across the 4 quads holding q=lc, divide, store ----
  float rs = lsum;
  rs += __shfl_xor(rs, 16);
  rs += __shfl_xor(rs, 32);   // every lane now holds l[q = lane&15]
#pragma unroll
  for (int r = 0; r < 4; ++r) {
    float inv = 1.0f / __shfl(rs, quad * 4 + r);
    int row = b * SEQ + qt * 128 + wave * 16 + quad * 4 + r;
#pragma unroll
    for (int n2 = 0; n2 < 4; ++n2) {
      int col = h * HD + n2 * 16 + lc;
      out[(size_t)row * HIDDEN + col] = f2bf(oacc[n2][r] * inv);
    }
  }
}

// ---------------- launch ----------------
extern "C" void kernel_launch(void* const* d_in, const int* in_sizes, int n_in,
                              void* d_out, int out_size, void* d_ws, size_t ws_size,
                              hipStream_t stream) {
  const float* x    = (const float*)d_in[0];
  const float* ln1g = (const float*)d_in[1];
  const float* ln1b = (const float*)d_in[2];
  const float* wq   = (const float*)d_in[3];
  const float* wk   = (const float*)d_in[4];
  const float* wv   = (const float*)d_in[5];
  const float* wo   = (const float*)d_in[6];
  const float* bo   = (const float*)d_in[7];
  const float* ln2g = (const float*)d_in[8];
  const float* ln2b = (const float*)d_in[9];
  const float* w1   = (const float*)d_in[10];
  const float* b1   = (const float*)d_in[11];
  const float* w2   = (const float*)d_in[12];
  const float* b2   = (const float*)d_in[13];

  auto rup = [](size_t b) { return (b + 255) & ~(size_t)255; };
  const size_t wbytes = rup((size_t)3 * HIDDEN * HIDDEN * 2) +
                        rup((size_t)HIDDEN * HIDDEN * 2) +
                        rup((size_t)MLPH * HIDDEN * 2) +
                        rup((size_t)HIDDEN * MLPH * 2);

  int R = SEQ;
  const int cands[4] = {16384, 8192, 4096, 2048};
  for (int i = 0; i < 4; ++i) {
    size_t need = wbytes + rup((size_t)cands[i] * 1536) + rup((size_t)cands[i] * 6144)
                         + rup((size_t)cands[i] * 1536);   // + vtg
    if (need <= ws_size) { R = cands[i]; break; }
  }

  char* ws = (char*)d_ws;
  size_t off = 0;
  auto alloc = [&](size_t bytes) {
    char* p = ws + off;
    off += (bytes + 255) & ~(size_t)255;
    return p;
  };
  short* wqkvb = (short*)alloc((size_t)3 * HIDDEN * HIDDEN * 2);
  short* wob   = (short*)alloc((size_t)HIDDEN * HIDDEN * 2);
  short* w1t   = (short*)alloc((size_t)MLPH * HIDDEN * 2);
  short* w2t   = (short*)alloc((size_t)HIDDEN * MLPH * 2);
  short* slotA = (short*)alloc((size_t)R * 1536);  // xn1 -> attn -> xn2
  short* bigR  = (short*)alloc((size_t)R * 6144);  // qkv  -> hdn
  short* vtg   = (short*)alloc((size_t)R * 1536);  // pre-swizzled V^T tiles

  conv_weights<<<(HIDDEN * HIDDEN + 255) / 256, 256, 0, stream>>>(
      wq, wk, wv, wo, wqkvb, wob);
  wtrans_kernel<<<dim3(MLPH / 64, HIDDEN / 64), 256, 0, stream>>>(
      w1, w1t, HIDDEN, MLPH);
  wtrans_kernel<<<dim3(HIDDEN / 64, MLPH / 64), 256, 0, stream>>>(
      w2, w2t, MLPH, HIDDEN);

  const int nch = MTOT / R;
  for (int c = 0; c < nch; ++c) {
    const float* xc  = x + (size_t)c * R * HIDDEN;
    float*       x2c = (float*)d_out + (size_t)c * R * HIDDEN;

    ln_kernel<<<R, 256, 0, stream>>>(xc, ln1g, ln1b, slotA);
    gemm_bt2<1, false, false, false, true, true>
        <<<dim3((3 * HIDDEN) / 256, R / 256), 512, 0, stream>>>(
        slotA, wqkvb, nullptr, nullptr, bigR, vtg, R, 3 * HIDDEN, HIDDEN);
    attn_kernel<<<dim3(SEQ / 128, HEADS, R / SEQ), 512, 0, stream>>>(
        bigR, vtg, slotA);
    gemm_bt2<0, true, false, true>
        <<<dim3(HIDDEN / 256, R / 256), 512, 0, stream>>>(
        slotA, wob, bo, xc, x2c, nullptr, R, HIDDEN, HIDDEN);
    ln_kernel<<<R, 256, 0, stream>>>(x2c, ln2g, ln2b, slotA);
    gemm_bt2<1, true, true, false>
        <<<dim3(MLPH / 256, R / 256), 512, 0, stream>>>(
        slotA, w1t, b1, nullptr, bigR, nullptr, R, MLPH, HIDDEN);
    gemm_bt2<0, true, false, true>
        <<<dim3(HIDDEN / 256, R / 256), 512, 0, stream>>>(
        bigR, w2t, b2, x2c, x2c, nullptr, R, HIDDEN, MLPH);
  }
}

// Round 12
// 560.718 us; speedup vs baseline: 1.0505x; 1.0505x over previous
//
#include <hip/hip_runtime.h>
#include <hip/hip_bf16.h>

#define HIDDEN 768
#define MLPH   3072
#define HEADS  12
#define HD     64
#define SEQ    1024
#define BATCH  16
#define MTOT   (BATCH*SEQ)   // 16384

typedef __attribute__((ext_vector_type(8))) short  short8;
typedef __attribute__((ext_vector_type(4))) short  short4x;
typedef __attribute__((ext_vector_type(8))) __bf16 bf16x8;
typedef __attribute__((ext_vector_type(4))) float  floatx4;

#define CL2 0.18033688011112042f   // 0.125 * log2(e): QK scale folded to exp2 domain

__device__ inline short f2bf(float f) {
  __hip_bfloat16 h = __float2bfloat16(f);
  return *reinterpret_cast<short*>(&h);
}

__device__ inline floatx4 mfma_bf16(short8 a, short8 b, floatx4 c) {
  return __builtin_amdgcn_mfma_f32_16x16x32_bf16(
      __builtin_bit_cast(bf16x8, a), __builtin_bit_cast(bf16x8, b), c, 0, 0, 0);
}

__device__ inline void gl_lds16(const short* g, short* l) {
  __builtin_amdgcn_global_load_lds(
      (const __attribute__((address_space(1))) unsigned int*)g,
      (__attribute__((address_space(3))) unsigned int*)l, 16, 0, 0);
}

// fast GELU: tanh form via v_exp_f32 + v_rcp_f32 (~10 VALU vs ~80 for erff).
// r7-validated: absmax unchanged (0.03125); MLP1 124 -> 99 us.
__device__ inline float gelu_f(float x) {
  float z = 0.7978845608028654f * (x + 0.044715f * x * x * x);
  float e = __builtin_amdgcn_exp2f(z * 2.8853900817779268f);  // exp(2z)
  float t = 1.0f - 2.0f * __builtin_amdgcn_rcpf(e + 1.0f);    // tanh(z)
  return 0.5f * x * (1.0f + t);
}

// ---------------- weight conversion (straight copies only) ----------------
__global__ __launch_bounds__(256) void conv_weights(
    const float* __restrict__ wq, const float* __restrict__ wk,
    const float* __restrict__ wv, const float* __restrict__ wo,
    short* __restrict__ wqkvb, short* __restrict__ wob)
{
  int i = blockIdx.x * 256 + threadIdx.x;
  const int HH = HIDDEN * HIDDEN;
  if (i < HH) {
    wqkvb[i]        = f2bf(wq[i]);
    wqkvb[HH + i]   = f2bf(wk[i]);
    wqkvb[2*HH + i] = f2bf(wv[i]);
    wob[i]          = f2bf(wo[i]);
  }
}

// ---------------- tiled f32->bf16 weight transpose: out[n][k] = in[k][n] ----
__global__ __launch_bounds__(256) void wtrans_kernel(
    const float* __restrict__ in, short* __restrict__ out, int RK, int CN)
{
  __shared__ float T[64][65];
  int n0 = blockIdx.x * 64, k0 = blockIdx.y * 64;
  int tx = threadIdx.x & 63, ty = threadIdx.x >> 6;   // 64 x 4
#pragma unroll
  for (int r = ty; r < 64; r += 4)
    T[r][tx] = in[(size_t)(k0 + r) * CN + n0 + tx];
  __syncthreads();
#pragma unroll
  for (int r = ty; r < 64; r += 4)
    out[(size_t)(n0 + r) * RK + k0 + tx] = f2bf(T[tx][r]);
}

// ---------------- layernorm (fp32 in, bf16 out) ----------------
__global__ __launch_bounds__(256) void ln_kernel(
    const float* __restrict__ x, const float* __restrict__ g,
    const float* __restrict__ b, short* __restrict__ out)
{
  int row = blockIdx.x;
  const float* xr = x + (size_t)row * HIDDEN;
  int t = threadIdx.x;
  float v0 = xr[t], v1 = xr[t + 256], v2 = xr[t + 512];
  float s  = v0 + v1 + v2;
  float s2 = v0*v0 + v1*v1 + v2*v2;
  for (int off = 32; off > 0; off >>= 1) {
    s  += __shfl_down(s, off);
    s2 += __shfl_down(s2, off);
  }
  __shared__ float red[8];
  __shared__ float stats[2];
  int wave = t >> 6;
  if ((t & 63) == 0) { red[wave] = s; red[4 + wave] = s2; }
  __syncthreads();
  if (t == 0) {
    float S  = red[0] + red[1] + red[2] + red[3];
    float S2 = red[4] + red[5] + red[6] + red[7];
    float mu  = S * (1.0f / HIDDEN);
    float var = S2 * (1.0f / HIDDEN) - mu * mu;
    stats[0] = mu;
    stats[1] = rsqrtf(var + 1e-5f);
  }
  __syncthreads();
  float mu = stats[0], rs = stats[1];
  short* orow = out + (size_t)row * HIDDEN;
  orow[t]       = f2bf((v0 - mu) * rs * g[t]       + b[t]);
  orow[t + 256] = f2bf((v1 - mu) * rs * g[t + 256] + b[t + 256]);
  orow[t + 512] = f2bf((v2 - mu) * rs * g[t + 512] + b[t + 512]);
}

// ---------------- BT-GEMM v4 (r7 champion — sync structure FROZEN) ---------
template<int OUTMODE /*0=f32,1=bf16*/, bool BIAS, bool GELU_E, bool RES,
         bool SCALEQ = false, bool VSPLIT = false>
__global__ __launch_bounds__(512, 2) void gemm_bt2(
    const short* __restrict__ A, const short* __restrict__ B,
    const float* __restrict__ bias, const float* __restrict__ res,
    void* __restrict__ out, short* __restrict__ vout, int M, int N, int K)
{
  __shared__ alignas(16) short As[2][2][8192];   // [slot][ks][256x32] = 64 KiB
  __shared__ alignas(16) short Bs[2][2][8192];   // 64 KiB

  int tid = threadIdx.x;
  int lane = tid & 63, wave = tid >> 6;
  int wr = wave >> 2, wc = wave & 3;          // 2 x 4 wave grid -> 128x64/wave
  int quad = lane >> 4, lc = lane & 15;

  // ---- XCD-aware bijective block swizzle (T1) ----
  int nbx = gridDim.x;
  int nwg = nbx * gridDim.y;
  int orig = blockIdx.y * nbx + blockIdx.x;
  int q8 = nwg >> 3, r8 = nwg & 7;
  int xcd = orig & 7, sub = orig >> 3;
  int wg = (xcd < r8 ? xcd * (q8 + 1) : r8 * (q8 + 1) + (xcd - r8) * q8) + sub;
  int m0 = (wg / nbx) * 256;
  int n0 = (wg % nbx) * 256;

  int srow = tid >> 2;
  int skb  = (tid & 3) ^ ((srow >> 1) & 3);
  const short* ga = A + (size_t)(m0 + srow) * K + skb * 8;
  const short* gb = B + (size_t)(n0 + srow) * K + skb * 8;
  const size_t rowskip = (size_t)128 * K;
  int lb0 = wave * 512;   // wave-uniform LDS base (shorts); HW adds lane*16B

#define STAGE_R(MAT, gp, sl, ks, kt) {                         \
    const short* _g = (gp) + (size_t)(kt) * 64 + (ks) * 32;    \
    gl_lds16(_g,           &MAT[sl][ks][lb0]);                 \
    gl_lds16(_g + rowskip, &MAT[sl][ks][4096 + lb0]);          \
  }

  floatx4 acc[8][4];
#pragma unroll
  for (int i = 0; i < 8; ++i)
#pragma unroll
    for (int j = 0; j < 4; ++j) acc[i][j] = floatx4{0.f, 0.f, 0.f, 0.f};

  int apos = (quad ^ ((lc >> 1) & 3)) * 8;
#define RD(buf, r) (*(const short8*)&(buf)[(r) * 32 + apos])
#define MM4x4(IOFF)                                                     \
    _Pragma("unroll")                                                   \
    for (int i = 0; i < 4; ++i)                                         \
      _Pragma("unroll")                                                 \
      for (int j = 0; j < 4; ++j)                                       \
        acc[i + IOFF][j] = mfma_bf16(aF[i], bF[j], acc[i + IOFF][j]);

  int NK = K >> 6;   // 64-wide K-steps: K=768 -> 12, K=3072 -> 48

  STAGE_R(As, ga, 0, 0, 0); STAGE_R(Bs, gb, 0, 0, 0);
  STAGE_R(As, ga, 0, 1, 0); STAGE_R(Bs, gb, 0, 1, 0);

  for (int kt = 0; kt < NK; ++kt) {
    const int sl = kt & 1;
    const short (*as_)[8192] = As[sl];
    const short (*bs_)[8192] = Bs[sl];
    const int s2 = sl ^ 1;
    const bool st = (kt + 1 < NK);
    short8 aF[4], bF[4];

    // ===== ph0: ks0 x i0-3  (stage B-ks1(kt+1)) =====
    asm volatile("s_waitcnt vmcnt(2)" ::: "memory");
    __builtin_amdgcn_s_barrier();
    asm volatile("" ::: "memory");
#pragma unroll
    for (int i = 0; i < 4; ++i) aF[i] = RD(as_[0], wr * 128 + i * 16 + lc);
#pragma unroll
    for (int j = 0; j < 4; ++j) bF[j] = RD(bs_[0], wc * 64 + j * 16 + lc);
    if (st) STAGE_R(Bs, gb, s2, 1, kt + 1);
    asm volatile("s_waitcnt lgkmcnt(0)" ::: "memory");
    __builtin_amdgcn_sched_barrier(0);
    __builtin_amdgcn_s_setprio(1);
    MM4x4(0);
    __builtin_amdgcn_s_setprio(0);

    // ===== ph1: ks0 x i4-7  (stage B-ks0(kt+1)) =====
    __builtin_amdgcn_s_barrier();
    asm volatile("" ::: "memory");
#pragma unroll
    for (int i = 0; i < 4; ++i) aF[i] = RD(as_[0], wr * 128 + (i + 4) * 16 + lc);
    if (st) STAGE_R(Bs, gb, s2, 0, kt + 1);
    asm volatile("s_waitcnt lgkmcnt(0)" ::: "memory");
    __builtin_amdgcn_sched_barrier(0);
    __builtin_amdgcn_s_setprio(1);
    MM4x4(4);
    __builtin_amdgcn_s_setprio(0);

    // ===== ph2: ks1 x i0-3  (stage A-ks0(kt+1)) =====
    if (st) asm volatile("s_waitcnt vmcnt(4)" ::: "memory");
    else    asm volatile("s_waitcnt vmcnt(0)" ::: "memory");
    __builtin_amdgcn_s_barrier();
    asm volatile("" ::: "memory");
#pragma unroll
    for (int i = 0; i < 4; ++i) aF[i] = RD(as_[1], wr * 128 + i * 16 + lc);
#pragma unroll
    for (int j = 0; j < 4; ++j) bF[j] = RD(bs_[1], wc * 64 + j * 16 + lc);
    if (st) STAGE_R(As, ga, s2, 0, kt + 1);
    asm volatile("s_waitcnt lgkmcnt(0)" ::: "memory");
    __builtin_amdgcn_sched_barrier(0);
    __builtin_amdgcn_s_setprio(1);
    MM4x4(0);
    __builtin_amdgcn_s_setprio(0);

    // ===== ph3: ks1 x i4-7  (stage A-ks1(kt+1)) =====
    __builtin_amdgcn_s_barrier();
    asm volatile("" ::: "memory");
#pragma unroll
    for (int i = 0; i < 4; ++i) aF[i] = RD(as_[1], wr * 128 + (i + 4) * 16 + lc);
    if (st) STAGE_R(As, ga, s2, 1, kt + 1);
    asm volatile("s_waitcnt lgkmcnt(0)" ::: "memory");
    __builtin_amdgcn_sched_barrier(0);
    __builtin_amdgcn_s_setprio(1);
    MM4x4(4);
    __builtin_amdgcn_s_setprio(0);
  }
#undef STAGE_R
#undef RD
#undef MM4x4

  // epilogue: C row = quad*4+reg, col = lane&15 (m89-verified layout)
#pragma unroll
  for (int i = 0; i < 8; ++i)
#pragma unroll
    for (int j = 0; j < 4; ++j)
#pragma unroll
      for (int r = 0; r < 4; ++r) {
        int row = m0 + wr * 128 + i * 16 + quad * 4 + r;
        int col = n0 + wc * 64 + j * 16 + lc;
        float v = acc[i][j][r];
        if (BIAS)   v += bias[col];
        if (GELU_E) v = gelu_f(v);
        if (RES)    v += res[(size_t)row * N + col];
        if (SCALEQ && col < HIDDEN) v *= CL2;
        if (VSPLIT && col >= 2 * HIDDEN) {
          int b_ = row >> 10, rr = row & 1023, kt_ = rr >> 6, k_ = rr & 63;
          int ks_ = k_ >> 5, kk = k_ & 31;
          int hd = col - 2 * HIDDEN, h_ = hd >> 6, d_ = hd & 63;
          size_t idx = ((size_t)((b_ * HEADS + h_) * 16 + kt_)) * 4096
                     + ks_ * 2048 + d_ * 32
                     + (((kk >> 3) ^ ((d_ >> 1) & 3)) << 3) + (kk & 7);
          vout[idx] = f2bf(v);
        } else if (OUTMODE == 1) {
          ((short*)out)[(size_t)row * N + col] = f2bf(v);
        } else {
          ((float*)out)[(size_t)row * N + col] = v;
        }
      }
}

// ---------------- flash attention v6: K+V dbuf, 1 barrier/kt, XCD-clustered -
// r11 post-mortem: direct-global V put vmem latency in PV's critical path and
// the 8 q-blocks per (b,h) landed on 8 different XCDs (8x L2 re-fetch,
// FETCH=209MB). Fixes:
//  - V restored to LDS (r10 identity-map staging), double-buffered with K;
//    ONE barrier/kt: vmcnt(0)+barrier publishes K/V(kt), then stage K/V(kt+1)
//    into the OTHER slot (its reads completed before every wave reached this
//    barrier — same proven publish pattern as the GEMM).
//  - XCD-clustering swizzle: xcd = L&7 owns NB/64 (b,h) pairs; all 8
//    q-blocks of a (b,h) on one XCD -> K/V tiles fetched into one L2.
//    NB is always divisible by 64 (1536/768/384/192).
__global__ __launch_bounds__(512) void attn_kernel(
    const short* __restrict__ qkv, const short* __restrict__ vtg,
    short* __restrict__ out)
{
  int NB = gridDim.x * gridDim.y * gridDim.z;
  int L  = (blockIdx.z * gridDim.y + blockIdx.y) * gridDim.x + blockIdx.x;
  int xcd = L & 7, s = L >> 3;
  int per = NB >> 6;                    // (b,h) pairs per XCD
  int bh  = xcd * per + (s >> 3);
  int qt  = s & 7;                      // 0..7 (128 q rows each)
  int h   = bh % HEADS;
  int b   = bh / HEADS;
  int tid = threadIdx.x, lane = tid & 63, wave = tid >> 6;
  int quad = lane >> 4, lc = lane & 15;

  __shared__ alignas(16) short Qs[2 * 128 * 32];   // 16 KiB
  __shared__ alignas(16) short Ks[2][4096];        // 16 KiB (K dbuf)
  __shared__ alignas(16) short Vs[2][4096];        // 16 KiB (V^T dbuf)
  __shared__ alignas(16) short Ps[8][16 * 72];     // 18 KiB, padded rows

  const int LDQ = 3 * HIDDEN;  // 2304
  const short* qb = qkv + (size_t)(b * SEQ) * LDQ + h * HD;
  const short* kb = qb + HIDDEN;
  const short* vt = vtg + (size_t)((b * HEADS + h) * 16) * 4096;

  // ---- stage Q (once) + K0 + V0; prologue syncthreads drains all ----
  {
    int row = tid >> 2, blk = tid & 3;
    int kblk = blk ^ ((row >> 1) & 3);
#pragma unroll
    for (int t = 0; t < 2; ++t) {
      const short* g = qb + (size_t)(qt * 128 + row) * LDQ + t * 32 + kblk * 8;
      gl_lds16(g, &Qs[t * 4096 + wave * 512]);
    }
  }
  int srow = (tid >> 2) & 63;
  int sks  = tid >> 8;
  int skb  = (tid & 3) ^ ((srow >> 1) & 3);
  const short* kg0 = kb + (size_t)srow * LDQ + sks * 32 + skb * 8;
  const short* vg0 = vt + tid * 8;
  gl_lds16(kg0, &Ks[0][wave * 512]);
  gl_lds16(vg0, &Vs[0][wave * 512]);
  __syncthreads();   // Q + K0 + V0 resident (full drain)

  // hoisted Q fragments (B-operand: lane holds Q[q = wave*16+lc][d..])
  int pos = quad ^ ((lc >> 1) & 3);
  short8 aq[2];
#pragma unroll
  for (int ks = 0; ks < 2; ++ks)
    aq[ks] = *(const short8*)&Qs[ks * 4096 + (wave * 16 + lc) * 32 + pos * 8];

  floatx4 oacc[4];
#pragma unroll
  for (int n2 = 0; n2 < 4; ++n2) oacc[n2] = floatx4{0.f, 0.f, 0.f, 0.f};
  float lsum = 0.f;   // partial row-sum for q = wave*16+lc
  short* pw = &Ps[wave][0];

  for (int kt = 0; kt < 16; ++kt) {
    const int sl = kt & 1;
    if (kt) {
      // own K/V(kt) stage-writes drained, then block-wide publish
      asm volatile("s_waitcnt vmcnt(0)" ::: "memory");
      __builtin_amdgcn_s_barrier();
      asm volatile("" ::: "memory");
    }
    // stage K/V(kt+1) into the slot whose reads finished in iteration kt-1
    if (kt + 1 < 16) {
      gl_lds16(kg0 + (size_t)((kt + 1) * 64) * LDQ, &Ks[sl ^ 1][wave * 512]);
      gl_lds16(vg0 + (kt + 1) * 4096, &Vs[sl ^ 1][wave * 512]);
    }

    // ---- S^T = K Q^T : lane holds S^T[k = m2*16+quad*4+r][q = lc] ----
    floatx4 sacc[4];
#pragma unroll
    for (int m2 = 0; m2 < 4; ++m2) sacc[m2] = floatx4{0.f, 0.f, 0.f, 0.f};
#pragma unroll
    for (int ks = 0; ks < 2; ++ks) {
#pragma unroll
      for (int m2 = 0; m2 < 4; ++m2) {
        short8 ak = *(const short8*)&Ks[sl][ks * 2048 + (m2 * 16 + lc) * 32 + pos * 8];
        sacc[m2] = mfma_bf16(ak, aq[ks], sacc[m2]);
      }
    }

    // ---- exp2, accumulate l, pack 4 consecutive-k bf16 -> one b64 write ----
#pragma unroll
    for (int m2 = 0; m2 < 4; ++m2) {
      float p0 = exp2f(sacc[m2][0]);
      float p1 = exp2f(sacc[m2][1]);
      float p2 = exp2f(sacc[m2][2]);
      float p3 = exp2f(sacc[m2][3]);
      lsum += (p0 + p1) + (p2 + p3);
      short4x pk;
      pk[0] = f2bf(p0); pk[1] = f2bf(p1); pk[2] = f2bf(p2); pk[3] = f2bf(p3);
      *(short4x*)&pw[lc * 72 + m2 * 16 + quad * 4] = pk;
    }
    // wave-private LDS handoff: wait own ds ops, pin the schedule (rule 18)
    asm volatile("s_waitcnt lgkmcnt(0)" ::: "memory");
    __builtin_amdgcn_sched_barrier(0);

    // ---- O += P @ V  (A = P rows q=lc; B = V^T rows d, from LDS) ----
#pragma unroll
    for (int ks = 0; ks < 2; ++ks) {
      short8 ap = *(const short8*)&pw[lc * 72 + (ks * 4 + quad) * 8];
#pragma unroll
      for (int n2 = 0; n2 < 4; ++n2) {
        short8 bv = *(const short8*)&Vs[sl][ks * 2048 + (n2 * 16 + lc) * 32 + pos * 8];
        oacc[n2] = mfma_bf16(ap, bv, oacc[n2]);
      }
    }
    // no trailing barrier: next iteration's vmcnt(0)+barrier orders all
  }

  // ---- epilogue: reduce l across the 4 quads holding q=lc, divide, store ----
  float rs = lsum;
  rs += __shfl_xor(rs, 16);
  rs += __shfl_xor(rs, 32);   // every lane now holds l[q = lane&15]
#pragma unroll
  for (int r = 0; r < 4; ++r) {
    float inv = 1.0f / __shfl(rs, quad * 4 + r);
    int row = b * SEQ + qt * 128 + wave * 16 + quad * 4 + r;
#pragma unroll
    for (int n2 = 0; n2 < 4; ++n2) {
      int col = h * HD + n2 * 16 + lc;
      out[(size_t)row * HIDDEN + col] = f2bf(oacc[n2][r] * inv);
    }
  }
}

// ---------------- launch ----------------
extern "C" void kernel_launch(void* const* d_in, const int* in_sizes, int n_in,
                              void* d_out, int out_size, void* d_ws, size_t ws_size,
                              hipStream_t stream) {
  const float* x    = (const float*)d_in[0];
  const float* ln1g = (const float*)d_in[1];
  const float* ln1b = (const float*)d_in[2];
  const float* wq   = (const float*)d_in[3];
  const float* wk   = (const float*)d_in[4];
  const float* wv   = (const float*)d_in[5];
  const float* wo   = (const float*)d_in[6];
  const float* bo   = (const float*)d_in[7];
  const float* ln2g = (const float*)d_in[8];
  const float* ln2b = (const float*)d_in[9];
  const float* w1   = (const float*)d_in[10];
  const float* b1   = (const float*)d_in[11];
  const float* w2   = (const float*)d_in[12];
  const float* b2   = (const float*)d_in[13];

  auto rup = [](size_t b) { return (b + 255) & ~(size_t)255; };
  const size_t wbytes = rup((size_t)3 * HIDDEN * HIDDEN * 2) +
                        rup((size_t)HIDDEN * HIDDEN * 2) +
                        rup((size_t)MLPH * HIDDEN * 2) +
                        rup((size_t)HIDDEN * MLPH * 2);

  int R = SEQ;
  const int cands[4] = {16384, 8192, 4096, 2048};
  for (int i = 0; i < 4; ++i) {
    size_t need = wbytes + rup((size_t)cands[i] * 1536) + rup((size_t)cands[i] * 6144)
                         + rup((size_t)cands[i] * 1536);   // + vtg
    if (need <= ws_size) { R = cands[i]; break; }
  }

  char* ws = (char*)d_ws;
  size_t off = 0;
  auto alloc = [&](size_t bytes) {
    char* p = ws + off;
    off += (bytes + 255) & ~(size_t)255;
    return p;
  };
  short* wqkvb = (short*)alloc((size_t)3 * HIDDEN * HIDDEN * 2);
  short* wob   = (short*)alloc((size_t)HIDDEN * HIDDEN * 2);
  short* w1t   = (short*)alloc((size_t)MLPH * HIDDEN * 2);
  short* w2t   = (short*)alloc((size_t)HIDDEN * MLPH * 2);
  short* slotA = (short*)alloc((size_t)R * 1536);  // xn1 -> attn -> xn2
  short* bigR  = (short*)alloc((size_t)R * 6144);  // qkv  -> hdn
  short* vtg   = (short*)alloc((size_t)R * 1536);  // pre-swizzled V^T tiles

  conv_weights<<<(HIDDEN * HIDDEN + 255) / 256, 256, 0, stream>>>(
      wq, wk, wv, wo, wqkvb, wob);
  wtrans_kernel<<<dim3(MLPH / 64, HIDDEN / 64), 256, 0, stream>>>(
      w1, w1t, HIDDEN, MLPH);
  wtrans_kernel<<<dim3(HIDDEN / 64, MLPH / 64), 256, 0, stream>>>(
      w2, w2t, MLPH, HIDDEN);

  const int nch = MTOT / R;
  for (int c = 0; c < nch; ++c) {
    const float* xc  = x + (size_t)c * R * HIDDEN;
    float*       x2c = (float*)d_out + (size_t)c * R * HIDDEN;

    ln_kernel<<<R, 256, 0, stream>>>(xc, ln1g, ln1b, slotA);
    gemm_bt2<1, false, false, false, true, true>
        <<<dim3((3 * HIDDEN) / 256, R / 256), 512, 0, stream>>>(
        slotA, wqkvb, nullptr, nullptr, bigR, vtg, R, 3 * HIDDEN, HIDDEN);
    attn_kernel<<<dim3(SEQ / 128, HEADS, R / SEQ), 512, 0, stream>>>(
        bigR, vtg, slotA);
    gemm_bt2<0, true, false, true>
        <<<dim3(HIDDEN / 256, R / 256), 512, 0, stream>>>(
        slotA, wob, bo, xc, x2c, nullptr, R, HIDDEN, HIDDEN);
    ln_kernel<<<R, 256, 0, stream>>>(x2c, ln2g, ln2b, slotA);
    gemm_bt2<1, true, true, false>
        <<<dim3(MLPH / 256, R / 256), 512, 0, stream>>>(
        slotA, w1t, b1, nullptr, bigR, nullptr, R, MLPH, HIDDEN);
    gemm_bt2<0, true, false, true>
        <<<dim3(HIDDEN / 256, R / 256), 512, 0, stream>>>(
        bigR, w2t, b2, x2c, x2c, nullptr, R, HIDDEN, MLPH);
  }
}

// Round 13
// 554.521 us; speedup vs baseline: 1.0622x; 1.0112x over previous
//
#include <hip/hip_runtime.h>
#include <hip/hip_bf16.h>

#define HIDDEN 768
#define MLPH   3072
#define HEADS  12
#define HD     64
#define SEQ    1024
#define BATCH  16
#define MTOT   (BATCH*SEQ)   // 16384

typedef __attribute__((ext_vector_type(8))) short  short8;
typedef __attribute__((ext_vector_type(4))) short  short4x;
typedef __attribute__((ext_vector_type(8))) __bf16 bf16x8;
typedef __attribute__((ext_vector_type(4))) float  floatx4;

#define CL2 0.18033688011112042f   // 0.125 * log2(e): QK scale folded to exp2 domain

__device__ inline short f2bf(float f) {
  __hip_bfloat16 h = __float2bfloat16(f);
  return *reinterpret_cast<short*>(&h);
}

__device__ inline floatx4 mfma_bf16(short8 a, short8 b, floatx4 c) {
  return __builtin_amdgcn_mfma_f32_16x16x32_bf16(
      __builtin_bit_cast(bf16x8, a), __builtin_bit_cast(bf16x8, b), c, 0, 0, 0);
}

__device__ inline void gl_lds16(const short* g, short* l) {
  __builtin_amdgcn_global_load_lds(
      (const __attribute__((address_space(1))) unsigned int*)g,
      (__attribute__((address_space(3))) unsigned int*)l, 16, 0, 0);
}

// fast GELU: tanh form via v_exp_f32 + v_rcp_f32 (~10 VALU vs ~80 for erff).
// r7-validated: absmax unchanged (0.03125); MLP1 124 -> 99 us.
__device__ inline float gelu_f(float x) {
  float z = 0.7978845608028654f * (x + 0.044715f * x * x * x);
  float e = __builtin_amdgcn_exp2f(z * 2.8853900817779268f);  // exp(2z)
  float t = 1.0f - 2.0f * __builtin_amdgcn_rcpf(e + 1.0f);    // tanh(z)
  return 0.5f * x * (1.0f + t);
}

// ---------------- weight conversion (straight copies; CL2 folded into wq) --
__global__ __launch_bounds__(256) void conv_weights(
    const float* __restrict__ wq, const float* __restrict__ wk,
    const float* __restrict__ wv, const float* __restrict__ wo,
    short* __restrict__ wqkvb, short* __restrict__ wob)
{
  int i = blockIdx.x * 256 + threadIdx.x;
  const int HH = HIDDEN * HIDDEN;
  if (i < HH) {
    wqkvb[i]        = f2bf(wq[i] * CL2);   // fold exp2-domain QK scale here
    wqkvb[HH + i]   = f2bf(wk[i]);
    wqkvb[2*HH + i] = f2bf(wv[i]);
    wob[i]          = f2bf(wo[i]);
  }
}

// ---------------- tiled f32->bf16 weight transpose: out[n][k] = in[k][n] ----
__global__ __launch_bounds__(256) void wtrans_kernel(
    const float* __restrict__ in, short* __restrict__ out, int RK, int CN)
{
  __shared__ float T[64][65];
  int n0 = blockIdx.x * 64, k0 = blockIdx.y * 64;
  int tx = threadIdx.x & 63, ty = threadIdx.x >> 6;   // 64 x 4
#pragma unroll
  for (int r = ty; r < 64; r += 4)
    T[r][tx] = in[(size_t)(k0 + r) * CN + n0 + tx];
  __syncthreads();
#pragma unroll
  for (int r = ty; r < 64; r += 4)
    out[(size_t)(n0 + r) * RK + k0 + tx] = f2bf(T[tx][r]);
}

// ---------------- layernorm (fp32 in, bf16 out) — float4/short4 (G13) ------
// 192 threads x float4 = 768 elements/row; 3-wave reduce. r12's scalar
// version was 4B-load/2B-store per lane (half the coalescing sweet spot).
__global__ __launch_bounds__(192) void ln_kernel(
    const float* __restrict__ x, const float* __restrict__ g,
    const float* __restrict__ b, short* __restrict__ out)
{
  int row = blockIdx.x;
  int t = threadIdx.x;
  float4 v = ((const float4*)(x + (size_t)row * HIDDEN))[t];
  float s  = (v.x + v.y) + (v.z + v.w);
  float s2 = (v.x*v.x + v.y*v.y) + (v.z*v.z + v.w*v.w);
  for (int off = 32; off > 0; off >>= 1) {
    s  += __shfl_down(s, off);
    s2 += __shfl_down(s2, off);
  }
  __shared__ float red[6];
  __shared__ float stats[2];
  int wave = t >> 6;
  if ((t & 63) == 0) { red[wave] = s; red[3 + wave] = s2; }
  __syncthreads();
  if (t == 0) {
    float S  = red[0] + red[1] + red[2];
    float S2 = red[3] + red[4] + red[5];
    float mu  = S * (1.0f / HIDDEN);
    float var = S2 * (1.0f / HIDDEN) - mu * mu;
    stats[0] = mu;
    stats[1] = rsqrtf(var + 1e-5f);
  }
  __syncthreads();
  float mu = stats[0], rs = stats[1];
  float4 gv = ((const float4*)g)[t];
  float4 bv = ((const float4*)b)[t];
  short4x o;
  o[0] = f2bf((v.x - mu) * rs * gv.x + bv.x);
  o[1] = f2bf((v.y - mu) * rs * gv.y + bv.y);
  o[2] = f2bf((v.z - mu) * rs * gv.z + bv.z);
  o[3] = f2bf((v.w - mu) * rs * gv.w + bv.w);
  *(short4x*)(out + (size_t)row * HIDDEN + t * 4) = o;
}

// ---------------- BT-GEMM v4 (r7 champion — sync structure FROZEN) ---------
template<int OUTMODE /*0=f32,1=bf16*/, bool BIAS, bool GELU_E, bool RES,
         bool VSPLIT = false>
__global__ __launch_bounds__(512, 2) void gemm_bt2(
    const short* __restrict__ A, const short* __restrict__ B,
    const float* __restrict__ bias, const float* __restrict__ res,
    void* __restrict__ out, short* __restrict__ vout, int M, int N, int K)
{
  __shared__ alignas(16) short As[2][2][8192];   // [slot][ks][256x32] = 64 KiB
  __shared__ alignas(16) short Bs[2][2][8192];   // 64 KiB

  int tid = threadIdx.x;
  int lane = tid & 63, wave = tid >> 6;
  int wr = wave >> 2, wc = wave & 3;          // 2 x 4 wave grid -> 128x64/wave
  int quad = lane >> 4, lc = lane & 15;

  // ---- XCD-aware bijective block swizzle (T1) ----
  int nbx = gridDim.x;
  int nwg = nbx * gridDim.y;
  int orig = blockIdx.y * nbx + blockIdx.x;
  int q8 = nwg >> 3, r8 = nwg & 7;
  int xcd = orig & 7, sub = orig >> 3;
  int wg = (xcd < r8 ? xcd * (q8 + 1) : r8 * (q8 + 1) + (xcd - r8) * q8) + sub;
  int m0 = (wg / nbx) * 256;
  int n0 = (wg % nbx) * 256;

  int srow = tid >> 2;
  int skb  = (tid & 3) ^ ((srow >> 1) & 3);
  const short* ga = A + (size_t)(m0 + srow) * K + skb * 8;
  const short* gb = B + (size_t)(n0 + srow) * K + skb * 8;
  const size_t rowskip = (size_t)128 * K;
  int lb0 = wave * 512;   // wave-uniform LDS base (shorts); HW adds lane*16B

#define STAGE_R(MAT, gp, sl, ks, kt) {                         \
    const short* _g = (gp) + (size_t)(kt) * 64 + (ks) * 32;    \
    gl_lds16(_g,           &MAT[sl][ks][lb0]);                 \
    gl_lds16(_g + rowskip, &MAT[sl][ks][4096 + lb0]);          \
  }

  floatx4 acc[8][4];
#pragma unroll
  for (int i = 0; i < 8; ++i)
#pragma unroll
    for (int j = 0; j < 4; ++j) acc[i][j] = floatx4{0.f, 0.f, 0.f, 0.f};

  int apos = (quad ^ ((lc >> 1) & 3)) * 8;
#define RD(buf, r) (*(const short8*)&(buf)[(r) * 32 + apos])
#define MM4x4(IOFF)                                                     \
    _Pragma("unroll")                                                   \
    for (int i = 0; i < 4; ++i)                                         \
      _Pragma("unroll")                                                 \
      for (int j = 0; j < 4; ++j)                                       \
        acc[i + IOFF][j] = mfma_bf16(aF[i], bF[j], acc[i + IOFF][j]);

  int NK = K >> 6;   // 64-wide K-steps: K=768 -> 12, K=3072 -> 48

  STAGE_R(As, ga, 0, 0, 0); STAGE_R(Bs, gb, 0, 0, 0);
  STAGE_R(As, ga, 0, 1, 0); STAGE_R(Bs, gb, 0, 1, 0);

  for (int kt = 0; kt < NK; ++kt) {
    const int sl = kt & 1;
    const short (*as_)[8192] = As[sl];
    const short (*bs_)[8192] = Bs[sl];
    const int s2 = sl ^ 1;
    const bool st = (kt + 1 < NK);
    short8 aF[4], bF[4];

    // ===== ph0: ks0 x i0-3  (stage B-ks1(kt+1)) =====
    asm volatile("s_waitcnt vmcnt(2)" ::: "memory");
    __builtin_amdgcn_s_barrier();
    asm volatile("" ::: "memory");
#pragma unroll
    for (int i = 0; i < 4; ++i) aF[i] = RD(as_[0], wr * 128 + i * 16 + lc);
#pragma unroll
    for (int j = 0; j < 4; ++j) bF[j] = RD(bs_[0], wc * 64 + j * 16 + lc);
    if (st) STAGE_R(Bs, gb, s2, 1, kt + 1);
    asm volatile("s_waitcnt lgkmcnt(0)" ::: "memory");
    __builtin_amdgcn_sched_barrier(0);
    __builtin_amdgcn_s_setprio(1);
    MM4x4(0);
    __builtin_amdgcn_s_setprio(0);

    // ===== ph1: ks0 x i4-7  (stage B-ks0(kt+1)) =====
    __builtin_amdgcn_s_barrier();
    asm volatile("" ::: "memory");
#pragma unroll
    for (int i = 0; i < 4; ++i) aF[i] = RD(as_[0], wr * 128 + (i + 4) * 16 + lc);
    if (st) STAGE_R(Bs, gb, s2, 0, kt + 1);
    asm volatile("s_waitcnt lgkmcnt(0)" ::: "memory");
    __builtin_amdgcn_sched_barrier(0);
    __builtin_amdgcn_s_setprio(1);
    MM4x4(4);
    __builtin_amdgcn_s_setprio(0);

    // ===== ph2: ks1 x i0-3  (stage A-ks0(kt+1)) =====
    if (st) asm volatile("s_waitcnt vmcnt(4)" ::: "memory");
    else    asm volatile("s_waitcnt vmcnt(0)" ::: "memory");
    __builtin_amdgcn_s_barrier();
    asm volatile("" ::: "memory");
#pragma unroll
    for (int i = 0; i < 4; ++i) aF[i] = RD(as_[1], wr * 128 + i * 16 + lc);
#pragma unroll
    for (int j = 0; j < 4; ++j) bF[j] = RD(bs_[1], wc * 64 + j * 16 + lc);
    if (st) STAGE_R(As, ga, s2, 0, kt + 1);
    asm volatile("s_waitcnt lgkmcnt(0)" ::: "memory");
    __builtin_amdgcn_sched_barrier(0);
    __builtin_amdgcn_s_setprio(1);
    MM4x4(0);
    __builtin_amdgcn_s_setprio(0);

    // ===== ph3: ks1 x i4-7  (stage A-ks1(kt+1)) =====
    __builtin_amdgcn_s_barrier();
    asm volatile("" ::: "memory");
#pragma unroll
    for (int i = 0; i < 4; ++i) aF[i] = RD(as_[1], wr * 128 + (i + 4) * 16 + lc);
    if (st) STAGE_R(As, ga, s2, 1, kt + 1);
    asm volatile("s_waitcnt lgkmcnt(0)" ::: "memory");
    __builtin_amdgcn_sched_barrier(0);
    __builtin_amdgcn_s_setprio(1);
    MM4x4(4);
    __builtin_amdgcn_s_setprio(0);
  }
#undef STAGE_R
#undef RD
#undef MM4x4

  // epilogue: C row = quad*4+reg, col = lane&15 (m89-verified layout)
#pragma unroll
  for (int i = 0; i < 8; ++i)
#pragma unroll
    for (int j = 0; j < 4; ++j)
#pragma unroll
      for (int r = 0; r < 4; ++r) {
        int row = m0 + wr * 128 + i * 16 + quad * 4 + r;
        int col = n0 + wc * 64 + j * 16 + lc;
        float v = acc[i][j][r];
        if (BIAS)   v += bias[col];
        if (GELU_E) v = gelu_f(v);
        if (RES)    v += res[(size_t)row * N + col];
        if (VSPLIT && col >= 2 * HIDDEN) {
          int b_ = row >> 10, rr = row & 1023, kt_ = rr >> 6, k_ = rr & 63;
          int ks_ = k_ >> 5, kk = k_ & 31;
          int hd = col - 2 * HIDDEN, h_ = hd >> 6, d_ = hd & 63;
          size_t idx = ((size_t)((b_ * HEADS + h_) * 16 + kt_)) * 4096
                     + ks_ * 2048 + d_ * 32
                     + (((kk >> 3) ^ ((d_ >> 1) & 3)) << 3) + (kk & 7);
          vout[idx] = f2bf(v);
        } else if (OUTMODE == 1) {
          ((short*)out)[(size_t)row * N + col] = f2bf(v);
        } else {
          ((float*)out)[(size_t)row * N + col] = v;
        }
      }
}

// ---------------- flash attention v6: K+V dbuf, 1 barrier/kt, XCD-clustered -
// (r12-validated: attn dropped below top-5; structure frozen)
__global__ __launch_bounds__(512) void attn_kernel(
    const short* __restrict__ qkv, const short* __restrict__ vtg,
    short* __restrict__ out)
{
  int NB = gridDim.x * gridDim.y * gridDim.z;
  int L  = (blockIdx.z * gridDim.y + blockIdx.y) * gridDim.x + blockIdx.x;
  int xcd = L & 7, s = L >> 3;
  int per = NB >> 6;                    // (b,h) pairs per XCD
  int bh  = xcd * per + (s >> 3);
  int qt  = s & 7;                      // 0..7 (128 q rows each)
  int h   = bh % HEADS;
  int b   = bh / HEADS;
  int tid = threadIdx.x, lane = tid & 63, wave = tid >> 6;
  int quad = lane >> 4, lc = lane & 15;

  __shared__ alignas(16) short Qs[2 * 128 * 32];   // 16 KiB
  __shared__ alignas(16) short Ks[2][4096];        // 16 KiB (K dbuf)
  __shared__ alignas(16) short Vs[2][4096];        // 16 KiB (V^T dbuf)
  __shared__ alignas(16) short Ps[8][16 * 72];     // 18 KiB, padded rows

  const int LDQ = 3 * HIDDEN;  // 2304
  const short* qb = qkv + (size_t)(b * SEQ) * LDQ + h * HD;
  const short* kb = qb + HIDDEN;
  const short* vt = vtg + (size_t)((b * HEADS + h) * 16) * 4096;

  // ---- stage Q (once) + K0 + V0; prologue syncthreads drains all ----
  {
    int row = tid >> 2, blk = tid & 3;
    int kblk = blk ^ ((row >> 1) & 3);
#pragma unroll
    for (int t = 0; t < 2; ++t) {
      const short* g = qb + (size_t)(qt * 128 + row) * LDQ + t * 32 + kblk * 8;
      gl_lds16(g, &Qs[t * 4096 + wave * 512]);
    }
  }
  int srow = (tid >> 2) & 63;
  int sks  = tid >> 8;
  int skb  = (tid & 3) ^ ((srow >> 1) & 3);
  const short* kg0 = kb + (size_t)srow * LDQ + sks * 32 + skb * 8;
  const short* vg0 = vt + tid * 8;
  gl_lds16(kg0, &Ks[0][wave * 512]);
  gl_lds16(vg0, &Vs[0][wave * 512]);
  __syncthreads();   // Q + K0 + V0 resident (full drain)

  // hoisted Q fragments (B-operand: lane holds Q[q = wave*16+lc][d..])
  int pos = quad ^ ((lc >> 1) & 3);
  short8 aq[2];
#pragma unroll
  for (int ks = 0; ks < 2; ++ks)
    aq[ks] = *(const short8*)&Qs[ks * 4096 + (wave * 16 + lc) * 32 + pos * 8];

  floatx4 oacc[4];
#pragma unroll
  for (int n2 = 0; n2 < 4; ++n2) oacc[n2] = floatx4{0.f, 0.f, 0.f, 0.f};
  float lsum = 0.f;   // partial row-sum for q = wave*16+lc
  short* pw = &Ps[wave][0];

  for (int kt = 0; kt < 16; ++kt) {
    const int sl = kt & 1;
    if (kt) {
      // own K/V(kt) stage-writes drained, then block-wide publish
      asm volatile("s_waitcnt vmcnt(0)" ::: "memory");
      __builtin_amdgcn_s_barrier();
      asm volatile("" ::: "memory");
    }
    // stage K/V(kt+1) into the slot whose reads finished in iteration kt-1
    if (kt + 1 < 16) {
      gl_lds16(kg0 + (size_t)((kt + 1) * 64) * LDQ, &Ks[sl ^ 1][wave * 512]);
      gl_lds16(vg0 + (kt + 1) * 4096, &Vs[sl ^ 1][wave * 512]);
    }

    // ---- S^T = K Q^T : lane holds S^T[k = m2*16+quad*4+r][q = lc] ----
    floatx4 sacc[4];
#pragma unroll
    for (int m2 = 0; m2 < 4; ++m2) sacc[m2] = floatx4{0.f, 0.f, 0.f, 0.f};
#pragma unroll
    for (int ks = 0; ks < 2; ++ks) {
#pragma unroll
      for (int m2 = 0; m2 < 4; ++m2) {
        short8 ak = *(const short8*)&Ks[sl][ks * 2048 + (m2 * 16 + lc) * 32 + pos * 8];
        sacc[m2] = mfma_bf16(ak, aq[ks], sacc[m2]);
      }
    }

    // ---- exp2, accumulate l, pack 4 consecutive-k bf16 -> one b64 write ----
#pragma unroll
    for (int m2 = 0; m2 < 4; ++m2) {
      float p0 = exp2f(sacc[m2][0]);
      float p1 = exp2f(sacc[m2][1]);
      float p2 = exp2f(sacc[m2][2]);
      float p3 = exp2f(sacc[m2][3]);
      lsum += (p0 + p1) + (p2 + p3);
      short4x pk;
      pk[0] = f2bf(p0); pk[1] = f2bf(p1); pk[2] = f2bf(p2); pk[3] = f2bf(p3);
      *(short4x*)&pw[lc * 72 + m2 * 16 + quad * 4] = pk;
    }
    // wave-private LDS handoff: wait own ds ops, pin the schedule (rule 18)
    asm volatile("s_waitcnt lgkmcnt(0)" ::: "memory");
    __builtin_amdgcn_sched_barrier(0);

    // ---- O += P @ V  (A = P rows q=lc; B = V^T rows d, from LDS) ----
#pragma unroll
    for (int ks = 0; ks < 2; ++ks) {
      short8 ap = *(const short8*)&pw[lc * 72 + (ks * 4 + quad) * 8];
#pragma unroll
      for (int n2 = 0; n2 < 4; ++n2) {
        short8 bv = *(const short8*)&Vs[sl][ks * 2048 + (n2 * 16 + lc) * 32 + pos * 8];
        oacc[n2] = mfma_bf16(ap, bv, oacc[n2]);
      }
    }
    // no trailing barrier: next iteration's vmcnt(0)+barrier orders all
  }

  // ---- epilogue: reduce l across the 4 quads holding q=lc, divide, store ----
  float rs = lsum;
  rs += __shfl_xor(rs, 16);
  rs += __shfl_xor(rs, 32);   // every lane now holds l[q = lane&15]
#pragma unroll
  for (int r = 0; r < 4; ++r) {
    float inv = 1.0f / __shfl(rs, quad * 4 + r);
    int row = b * SEQ + qt * 128 + wave * 16 + quad * 4 + r;
#pragma unroll
    for (int n2 = 0; n2 < 4; ++n2) {
      int col = h * HD + n2 * 16 + lc;
      out[(size_t)row * HIDDEN + col] = f2bf(oacc[n2][r] * inv);
    }
  }
}

// ---------------- launch ----------------
extern "C" void kernel_launch(void* const* d_in, const int* in_sizes, int n_in,
                              void* d_out, int out_size, void* d_ws, size_t ws_size,
                              hipStream_t stream) {
  const float* x    = (const float*)d_in[0];
  const float* ln1g = (const float*)d_in[1];
  const float* ln1b = (const float*)d_in[2];
  const float* wq   = (const float*)d_in[3];
  const float* wk   = (const float*)d_in[4];
  const float* wv   = (const float*)d_in[5];
  const float* wo   = (const float*)d_in[6];
  const float* bo   = (const float*)d_in[7];
  const float* ln2g = (const float*)d_in[8];
  const float* ln2b = (const float*)d_in[9];
  const float* w1   = (const float*)d_in[10];
  const float* b1   = (const float*)d_in[11];
  const float* w2   = (const float*)d_in[12];
  const float* b2   = (const float*)d_in[13];

  auto rup = [](size_t b) { return (b + 255) & ~(size_t)255; };

  int R = SEQ;
  const int cands[4] = {16384, 8192, 4096, 2048};
  {
    const size_t wbytes = rup((size_t)3 * HIDDEN * HIDDEN * 2) +
                          rup((size_t)HIDDEN * HIDDEN * 2) +
                          rup((size_t)MLPH * HIDDEN * 2) +
                          rup((size_t)HIDDEN * MLPH * 2);
    for (int i = 0; i < 4; ++i) {
      size_t need = wbytes + rup((size_t)cands[i] * 1536) + rup((size_t)cands[i] * 6144)
                           + rup((size_t)cands[i] * 1536);   // + vtg
      if (need <= ws_size) { R = cands[i]; break; }
    }
  }

  char* ws = (char*)d_ws;
  size_t off = 0;
  auto alloc = [&](size_t bytes) {
    char* p = ws + off;
    off += (bytes + 255) & ~(size_t)255;
    return p;
  };
  short* wqkvb = (short*)alloc((size_t)3 * HIDDEN * HIDDEN * 2);
  short* wob   = (short*)alloc((size_t)HIDDEN * HIDDEN * 2);
  short* w1t   = (short*)alloc((size_t)MLPH * HIDDEN * 2);
  short* w2t   = (short*)alloc((size_t)HIDDEN * MLPH * 2);
  short* slotA = (short*)alloc((size_t)R * 1536);  // xn1 -> attn -> xn2
  short* bigR  = (short*)alloc((size_t)R * 6144);  // qkv  -> hdn
  short* vtg   = (short*)alloc((size_t)R * 1536);  // pre-swizzled V^T tiles

  conv_weights<<<(HIDDEN * HIDDEN + 255) / 256, 256, 0, stream>>>(
      wq, wk, wv, wo, wqkvb, wob);
  wtrans_kernel<<<dim3(MLPH / 64, HIDDEN / 64), 256, 0, stream>>>(
      w1, w1t, HIDDEN, MLPH);
  wtrans_kernel<<<dim3(HIDDEN / 64, MLPH / 64), 256, 0, stream>>>(
      w2, w2t, MLPH, HIDDEN);

  const int nch = MTOT / R;
  for (int c = 0; c < nch; ++c) {
    const float* xc  = x + (size_t)c * R * HIDDEN;
    float*       x2c = (float*)d_out + (size_t)c * R * HIDDEN;

    ln_kernel<<<R, 192, 0, stream>>>(xc, ln1g, ln1b, slotA);
    gemm_bt2<1, false, false, false, true>
        <<<dim3((3 * HIDDEN) / 256, R / 256), 512, 0, stream>>>(
        slotA, wqkvb, nullptr, nullptr, bigR, vtg, R, 3 * HIDDEN, HIDDEN);
    attn_kernel<<<dim3(SEQ / 128, HEADS, R / SEQ), 512, 0, stream>>>(
        bigR, vtg, slotA);
    gemm_bt2<0, true, false, true>
        <<<dim3(HIDDEN / 256, R / 256), 512, 0, stream>>>(
        slotA, wob, bo, xc, x2c, nullptr, R, HIDDEN, HIDDEN);
    ln_kernel<<<R, 192, 0, stream>>>(x2c, ln2g, ln2b, slotA);
    gemm_bt2<1, true, true, false>
        <<<dim3(MLPH / 256, R / 256), 512, 0, stream>>>(
        slotA, w1t, b1, nullptr, bigR, nullptr, R, MLPH, HIDDEN);
    gemm_bt2<0, true, false, true>
        <<<dim3(HIDDEN / 256, R / 256), 512, 0, stream>>>(
        bigR, w2t, b2, x2c, x2c, nullptr, R, HIDDEN, MLPH);
  }
}